// Round 2
// baseline (115.545 us; speedup 1.0000x reference)
//
#include <hip/hip_runtime.h>

#define B_N 524288

typedef __attribute__((ext_vector_type(8))) short bf16x8;
typedef __attribute__((ext_vector_type(16))) float f32x16;
typedef __attribute__((ext_vector_type(4))) int i32x4;

// ws blob layout (ushort units):
//   W2 frags: [ ((c*9+s)*64 + lane)*8 + j ]  -> 4*9*64*8 = 18432
//   W3 frags: 18432 + [ (s*64+lane)*8 + j ]  -> 9*64*8   = 4608
//   W1 frags: 23040 + [ (c*64+lane)*8 + j ]  -> 4*64*8   = 2048
// total 25088 ushort = 50176 B of d_ws
// Frag element j on lane: k = 16*s + 8*(lane>>5) + j, f = 32*c + (lane&31)
// k==K_real slot carries the bias (B-side gets a literal 1.0 there).

// bf16 round-to-nearest-even, pure integer (no __hip_bfloat16 structs:
// they are not trivially copyable -> __builtin_bit_cast rejects them).
__device__ __forceinline__ unsigned short f2b(float v) {
  unsigned u = __builtin_bit_cast(unsigned, v);
  unsigned r = (u + 0x7FFFu + ((u >> 16) & 1u)) >> 16;
  return (unsigned short)r;
}

__device__ __forceinline__ unsigned pk2(float a, float b) {
  return (unsigned)f2b(a) | ((unsigned)f2b(b) << 16);
}

__device__ __forceinline__ f32x16 zero16() {
  f32x16 z;
#pragma unroll
  for (int i = 0; i < 16; ++i) z[i] = 0.f;
  return z;
}

// Build B-operand frag for k-step s (s=0..7) from producer C-layout accs (with relu).
// Producer: lane holds feats 32c + 8q + 4h + d (reg=4q+d), col(row-idx)=lane&31.
// Consumer B-layout: lane needs k = 16s + 8h + j. Quads swap between lane pairs (l, l^32).
__device__ __forceinline__ i32x4 make_bfrag(const f32x16* acc, int s, int h) {
  const int c = s >> 1;
  const int base = (s & 1) * 8;  // regs [base, base+8) = quads q0=2(s&1), q1=q0+1
  const f32x16 a = acc[c];
  unsigned o0a = pk2(fmaxf(a[base + 0], 0.f), fmaxf(a[base + 1], 0.f));
  unsigned o0b = pk2(fmaxf(a[base + 2], 0.f), fmaxf(a[base + 3], 0.f));
  unsigned o1a = pk2(fmaxf(a[base + 4], 0.f), fmaxf(a[base + 5], 0.f));
  unsigned o1b = pk2(fmaxf(a[base + 6], 0.f), fmaxf(a[base + 7], 0.f));
  // h=0 lane needs partner's q0; h=1 lane needs partner's q1
  unsigned sa = h ? o0a : o1a;
  unsigned sb = h ? o0b : o1b;
  unsigned ra = (unsigned)__shfl_xor((int)sa, 32, 64);
  unsigned rb = (unsigned)__shfl_xor((int)sb, 32, 64);
  i32x4 v;
  v.x = h ? (int)ra : (int)o0a;
  v.y = h ? (int)rb : (int)o0b;
  v.z = h ? (int)o1a : (int)ra;
  v.w = h ? (int)o1b : (int)rb;
  return v;
}

__global__ __launch_bounds__(256) void prep_kernel(
    const float* __restrict__ W1, const float* __restrict__ b1,
    const float* __restrict__ W2, const float* __restrict__ b2,
    const float* __restrict__ W3, const float* __restrict__ b3,
    unsigned short* __restrict__ blob) {
  int idx = blockIdx.x * 256 + threadIdx.x;
  if (idx >= 3136) return;
  if (idx < 2304) {  // W2 frag chunks: idx = (c*9+s)*64 + lane
    int lane = idx & 63;
    int cs = idx >> 6;
    int c = cs / 9, s = cs % 9;
    int h = lane >> 5, f = 32 * c + (lane & 31);
#pragma unroll
    for (int j = 0; j < 8; ++j) {
      int k = 16 * s + 8 * h + j;
      float v = (k < 128) ? W2[k * 128 + f] : ((k == 128) ? b2[f] : 0.f);
      blob[idx * 8 + j] = f2b(v);
    }
  } else if (idx < 2880) {  // W3 frag chunks (M padded 3->32)
    int r = idx - 2304;
    int lane = r & 63, s = r >> 6;
    int h = lane >> 5, f = lane & 31;
#pragma unroll
    for (int j = 0; j < 8; ++j) {
      int k = 16 * s + 8 * h + j;
      float v = 0.f;
      if (f < 3) v = (k < 128) ? W3[k * 3 + f] : ((k == 128) ? b3[f] : 0.f);
      blob[18432 + r * 8 + j] = f2b(v);
    }
  } else {  // W1 frag chunks (K padded 5(+bias)->16)
    int r = idx - 2880;
    int lane = r & 63, c = r >> 6;
    int h = lane >> 5, f = 32 * c + (lane & 31);
#pragma unroll
    for (int j = 0; j < 8; ++j) {
      int k = 8 * h + j;
      float v = (k < 5) ? W1[k * 128 + f] : ((k == 5) ? b1[f] : 0.f);
      blob[23040 + r * 8 + j] = f2b(v);
    }
  }
}

__global__ __launch_bounds__(256) void dyn_kernel(
    const float* __restrict__ S, const float* __restrict__ A,
    const unsigned short* __restrict__ blob, float* __restrict__ out) {
  __shared__ __align__(16) unsigned short lds[23040];  // W2(36864B)+W3(9216B)
  const int tid = threadIdx.x;
  const int lane = tid & 63;
  const int wv = tid >> 6;
  const int h = lane >> 5;
  const int ln = lane & 31;

  // stage W2+W3 frag blob into LDS (frag-major: ds_read_b128 conflict-free)
  {
    const i32x4* src = (const i32x4*)blob;
    i32x4* dst = (i32x4*)lds;
    for (int i = tid; i < 2880; i += 256) dst[i] = src[i];
  }
  // W1 frags to regs (4 frags = 16 VGPR)
  i32x4 w1f[4];
  {
    const i32x4* w1p = (const i32x4*)(blob + 23040);
#pragma unroll
    for (int c = 0; c < 4; ++c) w1f[c] = w1p[c * 64 + lane];
  }
  __syncthreads();

  const int r0 = blockIdx.x * 256 + wv * 64;  // wave handles rows [r0, r0+64)
  const int row64 = r0 + lane;

  const float sx = S[row64 * 3 + 0], sy = S[row64 * 3 + 1], sz = S[row64 * 3 + 2];
  const float ax = A[row64 * 2 + 0], ay = A[row64 * 2 + 1];

  // ---- reward, fp32 (bf16 would break the boundary-gaussian terms) ----
  {
    float quad = 30.f * ((sx - ax) * (sx - ax) + (sy - ay) * (sy - ay));
    const float OX[6] = {0.f, 0.f, 0.f, 0.f, 0.f, -0.8f};
    const float OY[6] = {0.f, 0.2f, 0.4f, 0.6f, 0.8f, -0.8f};
    float gs = 0.f;
#pragma unroll
    for (int i = 0; i < 6; ++i) {
      float dx = sx - OX[i], dy = sy - OY[i];
      gs += __expf(-(dx * dx + dy * dy) * 14.285714285714286f);  // 1/(2*VAR)
    }
    float e1 = sx + 1.5f, e2 = sx - 1.5f, e3 = sy - 1.0f, e4 = sy + 1.0f;
    const float ib = 555.5555555555555f;  // 1/(2*SIG^2)
    float bnd = __expf(-e1 * e1 * ib) + __expf(-e2 * e2 * ib) +
                __expf(-e3 * e3 * ib) + __expf(-e4 * e4 * ib);
    // 100/(2*pi*VAR) = 454.728408834 ; 10/(SIG*sqrt(2*pi)) = 132.980760134
    out[3 * B_N + row64] = -(quad + 454.72840883398667f * gs + 132.98076013381091f * bnd);
  }

  const i32x4* w2p = (const i32x4*)lds;            // frag (c,s) at (c*9+s)*64 + lane
  const i32x4* w3p = (const i32x4*)(lds + 18432);  // frag (s) at s*64 + lane

#pragma unroll
  for (int t = 0; t < 2; ++t) {
    // x for row r0 + 32t + ln lives in lane (32t + ln); t=1 -> fetch from partner
    float v0 = t ? __shfl_xor(sx, 32, 64) : sx;
    float v1 = t ? __shfl_xor(sy, 32, 64) : sy;
    float v2 = t ? __shfl_xor(sz, 32, 64) : sz;
    float v3 = t ? __shfl_xor(ax, 32, 64) : ax;
    float v4 = t ? __shfl_xor(ay, 32, 64) : ay;

    // B1 frag: xT_pad[k][row]: h=0 lanes hold {s0,s1,s2,a0,a1,1,0,0}; h=1 all zero
    i32x4 xf;
    xf.x = h ? 0 : (int)pk2(v0, v1);
    xf.y = h ? 0 : (int)pk2(v2, v3);
    xf.z = h ? 0 : (int)pk2(v4, 1.0f);
    xf.w = 0;
    bf16x8 xb = __builtin_bit_cast(bf16x8, xf);

    // L1: h1T = W1T_pad(128x16) . xT_pad(16x32)  (bias folded at k=5)
    f32x16 acc1[4];
#pragma unroll
    for (int c = 0; c < 4; ++c)
      acc1[c] = __builtin_amdgcn_mfma_f32_32x32x16_bf16(
          __builtin_bit_cast(bf16x8, w1f[c]), xb, zero16(), 0, 0, 0);

    // relu + pack -> B2 frags (in-register transpose via lane-pair quad swap)
    i32x4 bf[9];
#pragma unroll
    for (int s = 0; s < 8; ++s) bf[s] = make_bfrag(acc1, s, h);
    {  // bias step: B[k=128][*] = 1.0 (bf16 0x3F80), rest 0
      i32x4 v;
      v.x = h ? 0 : 0x3F80;
      v.y = 0; v.z = 0; v.w = 0;
      bf[8] = v;
    }

    // L2: h2T = W2T_pad(128x144) . h1T_pad
    f32x16 acc2[4];
#pragma unroll
    for (int c = 0; c < 4; ++c) acc2[c] = zero16();
#pragma unroll
    for (int s = 0; s < 9; ++s) {
      bf16x8 bb = __builtin_bit_cast(bf16x8, bf[s]);
#pragma unroll
      for (int c = 0; c < 4; ++c) {
        bf16x8 aa = __builtin_bit_cast(bf16x8, w2p[(c * 9 + s) * 64 + lane]);
        acc2[c] = __builtin_amdgcn_mfma_f32_32x32x16_bf16(aa, bb, acc2[c], 0, 0, 0);
      }
    }

    // relu + pack -> B3 frags (bf[8] bias frag unchanged, reused for b3)
#pragma unroll
    for (int s = 0; s < 8; ++s) bf[s] = make_bfrag(acc2, s, h);

    // L3: s_nextT = W3T_pad(32x144) . h2T_pad  (only feats 0..2 nonzero)
    f32x16 acc3 = zero16();
#pragma unroll
    for (int s = 0; s < 9; ++s) {
      bf16x8 aa = __builtin_bit_cast(bf16x8, w3p[s * 64 + lane]);
      acc3 = __builtin_amdgcn_mfma_f32_32x32x16_bf16(
          aa, __builtin_bit_cast(bf16x8, bf[s]), acc3, 0, 0, 0);
    }

    // D3 C-layout: h=0 lanes, regs 0..2 = s_next[row][0..2]
    if (h == 0) {
      int row = r0 + 32 * t + ln;
      float* p = out + row * 3;
      p[0] = acc3[0];
      p[1] = acc3[1];
      p[2] = acc3[2];
    }
  }
}

extern "C" void kernel_launch(void* const* d_in, const int* in_sizes, int n_in,
                              void* d_out, int out_size, void* d_ws, size_t ws_size,
                              hipStream_t stream) {
  const float* S = (const float*)d_in[0];
  const float* A = (const float*)d_in[1];
  const float* W1 = (const float*)d_in[2];
  const float* b1 = (const float*)d_in[3];
  const float* W2 = (const float*)d_in[4];
  const float* b2 = (const float*)d_in[5];
  const float* W3 = (const float*)d_in[6];
  const float* b3 = (const float*)d_in[7];
  unsigned short* blob = (unsigned short*)d_ws;
  float* out = (float*)d_out;

  prep_kernel<<<dim3(13), dim3(256), 0, stream>>>(W1, b1, W2, b2, W3, b3, blob);
  dyn_kernel<<<dim3(B_N / 256), dim3(256), 0, stream>>>(S, A, blob, out);
}

// Round 3
// 105.100 us; speedup vs baseline: 1.0994x; 1.0994x over previous
//
#include <hip/hip_runtime.h>

#define B_N 524288

typedef __attribute__((ext_vector_type(8))) short bf16x8;
typedef __attribute__((ext_vector_type(16))) float f32x16;
typedef __attribute__((ext_vector_type(4))) int i32x4;

// ws blob layout (ushort units):
//   W2 frags: [ ((c*9+s)*64 + lane)*8 + j ]  -> 4*9*64*8 = 18432
//   W3 frags: 18432 + [ (s*64+lane)*8 + j ]  -> 9*64*8   = 4608
//   W1 frags: 23040 + [ (c*64+lane)*8 + j ]  -> 4*64*8   = 2048
// total 25088 ushort = 50176 B
//
// Frag element j on lane: k = 16*s + 8*(lane>>5) + j, f(=m) = 32*c + (lane&31)
// (A-operand k-map verified by R2 pass.)
//
// phi-trick: producer C-layout regs [8s'..8s'+7] packed in natural order land
// logical feature phi(k) at B position k, where phi(k) = k with bits 2<->3
// swapped. We bake phi into W2/W3's k index in prep, so the dyn kernel needs
// NO cross-lane exchange between layers (R2 used shfl_xor+cndmask).

__device__ __forceinline__ unsigned short f2b(float v) {  // RNE, prep only
  unsigned u = __builtin_bit_cast(unsigned, v);
  unsigned r = (u + 0x7FFFu + ((u >> 16) & 1u)) >> 16;
  return (unsigned short)r;
}

// pack 2 floats -> bf16x2 (round-half-up): 2 add + 1 v_perm
__device__ __forceinline__ unsigned pk2(float a, float b) {
  unsigned ua = __builtin_bit_cast(unsigned, a) + 0x8000u;
  unsigned ub = __builtin_bit_cast(unsigned, b) + 0x8000u;
  return __builtin_amdgcn_perm(ub, ua, 0x07060302u);  // {a.hi16, b.hi16}
}

// relu + pack
__device__ __forceinline__ unsigned pkr(float a, float b) {
  return pk2(fmaxf(a, 0.f), fmaxf(b, 0.f));
}

__device__ __forceinline__ f32x16 zero16() {
  f32x16 z;
#pragma unroll
  for (int i = 0; i < 16; ++i) z[i] = 0.f;
  return z;
}

// B-frag for k-step s from producer C accs, natural order (phi absorbed in W).
__device__ __forceinline__ i32x4 mkfrag(const f32x16* acc, int s) {
  const f32x16 a = acc[s >> 1];
  const int b = (s & 1) * 8;
  i32x4 v;
  v.x = (int)pkr(a[b + 0], a[b + 1]);
  v.y = (int)pkr(a[b + 2], a[b + 3]);
  v.z = (int)pkr(a[b + 4], a[b + 5]);
  v.w = (int)pkr(a[b + 6], a[b + 7]);
  return v;
}

__device__ __forceinline__ int phi(int k) {  // swap bits 2 and 3
  return (k & ~12) | ((k & 4) << 1) | ((k & 8) >> 1);
}

__global__ __launch_bounds__(256) void prep_kernel(
    const float* __restrict__ W1, const float* __restrict__ b1,
    const float* __restrict__ W2, const float* __restrict__ b2,
    const float* __restrict__ W3, const float* __restrict__ b3,
    unsigned short* __restrict__ blob) {
  int idx = blockIdx.x * 256 + threadIdx.x;
  if (idx >= 3136) return;
  if (idx < 2304) {  // W2 frags: idx = (c*9+s)*64 + lane, k-dim permuted by phi
    int lane = idx & 63;
    int cs = idx >> 6;
    int c = cs / 9, s = cs % 9;
    int h = lane >> 5, f = 32 * c + (lane & 31);
#pragma unroll
    for (int j = 0; j < 8; ++j) {
      int k = 16 * s + 8 * h + j;
      float v = (k < 128) ? W2[phi(k) * 128 + f] : ((k == 128) ? b2[f] : 0.f);
      blob[idx * 8 + j] = f2b(v);
    }
  } else if (idx < 2880) {  // W3 frags (M padded 3->32), k-dim permuted by phi
    int r = idx - 2304;
    int lane = r & 63, s = r >> 6;
    int h = lane >> 5, f = lane & 31;
#pragma unroll
    for (int j = 0; j < 8; ++j) {
      int k = 16 * s + 8 * h + j;
      float v = 0.f;
      if (f < 3) v = (k < 128) ? W3[phi(k) * 3 + f] : ((k == 128) ? b3[f] : 0.f);
      blob[18432 + r * 8 + j] = f2b(v);
    }
  } else {  // W1 frags (K padded 5(+bias)->16), natural
    int r = idx - 2880;
    int lane = r & 63, c = r >> 6;
    int h = lane >> 5, f = 32 * c + (lane & 31);
#pragma unroll
    for (int j = 0; j < 8; ++j) {
      int k = 8 * h + j;
      float v = (k < 5) ? W1[k * 128 + f] : ((k == 5) ? b1[f] : 0.f);
      blob[23040 + r * 8 + j] = f2b(v);
    }
  }
}

__global__ __launch_bounds__(256, 2) void dyn_kernel(
    const float* __restrict__ S, const float* __restrict__ A,
    const unsigned short* __restrict__ blob, float* __restrict__ out) {
  __shared__ __align__(16) unsigned short lds[25088];  // W2+W3+W1 frag blob
  const int tid = threadIdx.x;
  const int lane = tid & 63;
  const int wv = tid >> 6;
  const int h = lane >> 5;
  const int ln = lane & 31;

  {  // stage whole blob (50 KB) into LDS
    const i32x4* src = (const i32x4*)blob;
    i32x4* dst = (i32x4*)lds;
    for (int i = tid; i < 3136; i += 256) dst[i] = src[i];
  }
  __syncthreads();

  const i32x4* w2p = (const i32x4*)lds;            // (c*9+s)*64 + lane
  const i32x4* w3p = (const i32x4*)(lds + 18432);  // s*64 + lane
  const i32x4* w1p = (const i32x4*)(lds + 23040);  // c*64 + lane

  i32x4 w1f[4];
#pragma unroll
  for (int c = 0; c < 4; ++c) w1f[c] = w1p[c * 64 + lane];

  const int r0 = blockIdx.x * 256 + wv * 64;  // wave covers rows [r0, r0+64)
  const int row64 = r0 + lane;

  const float sx = S[row64 * 3 + 0], sy = S[row64 * 3 + 1], sz = S[row64 * 3 + 2];
  const float ax = A[row64 * 2 + 0], ay = A[row64 * 2 + 1];

  // ---- reward, fp32 (bf16 would break the boundary-gaussian terms) ----
  {
    float quad = 30.f * ((sx - ax) * (sx - ax) + (sy - ay) * (sy - ay));
    const float OX[6] = {0.f, 0.f, 0.f, 0.f, 0.f, -0.8f};
    const float OY[6] = {0.f, 0.2f, 0.4f, 0.6f, 0.8f, -0.8f};
    float gs = 0.f;
#pragma unroll
    for (int i = 0; i < 6; ++i) {
      float dx = sx - OX[i], dy = sy - OY[i];
      gs += __expf(-(dx * dx + dy * dy) * 14.285714285714286f);  // 1/(2*VAR)
    }
    float e1 = sx + 1.5f, e2 = sx - 1.5f, e3 = sy - 1.0f, e4 = sy + 1.0f;
    const float ib = 555.5555555555555f;  // 1/(2*SIG^2)
    float bnd = __expf(-e1 * e1 * ib) + __expf(-e2 * e2 * ib) +
                __expf(-e3 * e3 * ib) + __expf(-e4 * e4 * ib);
    out[3 * B_N + row64] = -(quad + 454.72840883398667f * gs + 132.98076013381091f * bnd);
  }

  // x frags for both 32-sample halves (t=1 data via lane-pair shuffle)
  const float u0 = __shfl_xor(sx, 32, 64), u1 = __shfl_xor(sy, 32, 64);
  const float u2 = __shfl_xor(sz, 32, 64), u3 = __shfl_xor(ax, 32, 64);
  const float u4 = __shfl_xor(ay, 32, 64);

  i32x4 xf[2];
  xf[0].x = h ? 0 : (int)pk2(sx, sy);
  xf[0].y = h ? 0 : (int)pk2(sz, ax);
  xf[0].z = h ? 0 : (int)pk2(ay, 1.0f);
  xf[0].w = 0;
  xf[1].x = h ? 0 : (int)pk2(u0, u1);
  xf[1].y = h ? 0 : (int)pk2(u2, u3);
  xf[1].z = h ? 0 : (int)pk2(u4, 1.0f);
  xf[1].w = 0;

  i32x4 bias_frag;  // B[k=128][*] = 1.0 on h=0 lanes, rest 0
  bias_frag.x = h ? 0 : 0x3F80;
  bias_frag.y = 0; bias_frag.z = 0; bias_frag.w = 0;

  // ---- L1 + pack (per half; keeps only one acc1 set live) ----
  i32x4 bf2[2][9];
#pragma unroll
  for (int t = 0; t < 2; ++t) {
    f32x16 acc1[4];
    bf16x8 xb = __builtin_bit_cast(bf16x8, xf[t]);
#pragma unroll
    for (int c = 0; c < 4; ++c)
      acc1[c] = __builtin_amdgcn_mfma_f32_32x32x16_bf16(
          __builtin_bit_cast(bf16x8, w1f[c]), xb, zero16(), 0, 0, 0);
#pragma unroll
    for (int s = 0; s < 8; ++s) bf2[t][s] = mkfrag(acc1, s);
    bf2[t][8] = bias_frag;
  }

  // ---- L2, both halves share each weight-frag read ----
  f32x16 acc2[2][4];
#pragma unroll
  for (int t = 0; t < 2; ++t)
#pragma unroll
    for (int c = 0; c < 4; ++c) acc2[t][c] = zero16();
#pragma unroll
  for (int s = 0; s < 9; ++s) {
    bf16x8 b0 = __builtin_bit_cast(bf16x8, bf2[0][s]);
    bf16x8 b1 = __builtin_bit_cast(bf16x8, bf2[1][s]);
#pragma unroll
    for (int c = 0; c < 4; ++c) {
      bf16x8 aa = __builtin_bit_cast(bf16x8, w2p[(c * 9 + s) * 64 + lane]);
      acc2[0][c] = __builtin_amdgcn_mfma_f32_32x32x16_bf16(aa, b0, acc2[0][c], 0, 0, 0);
      acc2[1][c] = __builtin_amdgcn_mfma_f32_32x32x16_bf16(aa, b1, acc2[1][c], 0, 0, 0);
    }
  }

  // ---- pack h2 ----
  i32x4 bf3[2][9];
#pragma unroll
  for (int t = 0; t < 2; ++t) {
#pragma unroll
    for (int s = 0; s < 8; ++s) bf3[t][s] = mkfrag(acc2[t], s);
    bf3[t][8] = bias_frag;
  }

  // ---- L3, shared weight-frag reads ----
  f32x16 acc3[2];
  acc3[0] = zero16();
  acc3[1] = zero16();
#pragma unroll
  for (int s = 0; s < 9; ++s) {
    bf16x8 aa = __builtin_bit_cast(bf16x8, w3p[s * 64 + lane]);
    acc3[0] = __builtin_amdgcn_mfma_f32_32x32x16_bf16(
        aa, __builtin_bit_cast(bf16x8, bf3[0][s]), acc3[0], 0, 0, 0);
    acc3[1] = __builtin_amdgcn_mfma_f32_32x32x16_bf16(
        aa, __builtin_bit_cast(bf16x8, bf3[1][s]), acc3[1], 0, 0, 0);
  }

  // ---- store s_next: C-layout h=0 lanes, regs 0..2 ----
  if (h == 0) {
#pragma unroll
    for (int t = 0; t < 2; ++t) {
      int row = r0 + 32 * t + ln;
      float* p = out + row * 3;
      p[0] = acc3[t][0];
      p[1] = acc3[t][1];
      p[2] = acc3[t][2];
    }
  }
}

extern "C" void kernel_launch(void* const* d_in, const int* in_sizes, int n_in,
                              void* d_out, int out_size, void* d_ws, size_t ws_size,
                              hipStream_t stream) {
  const float* S = (const float*)d_in[0];
  const float* A = (const float*)d_in[1];
  const float* W1 = (const float*)d_in[2];
  const float* b1 = (const float*)d_in[3];
  const float* W2 = (const float*)d_in[4];
  const float* b2 = (const float*)d_in[5];
  const float* W3 = (const float*)d_in[6];
  const float* b3 = (const float*)d_in[7];
  unsigned short* blob = (unsigned short*)d_ws;
  float* out = (float*)d_out;

  prep_kernel<<<dim3(13), dim3(256), 0, stream>>>(W1, b1, W2, b2, W3, b3, blob);
  dyn_kernel<<<dim3(B_N / 256), dim3(256), 0, stream>>>(S, A, blob, out);
}

// Round 5
// 103.061 us; speedup vs baseline: 1.1211x; 1.0198x over previous
//
#include <hip/hip_runtime.h>

#define B_N 524288

typedef __attribute__((ext_vector_type(8))) short bf16x8;
typedef __attribute__((ext_vector_type(16))) float f32x16;
typedef __attribute__((ext_vector_type(4))) int i32x4;

// ws blob layout (ushort units):
//   W2 frags: [ ((c*9+s)*64 + lane)*8 + j ]  -> 4*9*64*8 = 18432
//   W3 frags: 18432 + [ (s*64+lane)*8 + j ]  -> 9*64*8   = 4608
//   W1 frags: 23040 + [ (c*64+lane)*8 + j ]  -> 4*64*8   = 2048
// total 25088 ushort = 50176 B
//
// Frag element j on lane: k = 16*s + 8*(lane>>5) + j, f(=m) = 32*c + (lane&31)
// (A-operand k-map verified by R2 pass; phi-trick verified by R3 pass.)
// phi(k) = k with bits 2<->3 swapped, baked into W2/W3 k-index so the packed
// producer C-layout feeds the next layer's B operand with NO cross-lane ops.

__device__ __forceinline__ unsigned short f2b(float v) {  // RNE, prep only
  unsigned u = __builtin_bit_cast(unsigned, v);
  unsigned r = (u + 0x7FFFu + ((u >> 16) & 1u)) >> 16;
  return (unsigned short)r;
}

// pack 2 floats -> bf16x2 (round-half-up): 2 add + 1 v_perm
__device__ __forceinline__ unsigned pk2(float a, float b) {
  unsigned ua = __builtin_bit_cast(unsigned, a) + 0x8000u;
  unsigned ub = __builtin_bit_cast(unsigned, b) + 0x8000u;
  return __builtin_amdgcn_perm(ub, ua, 0x07060302u);  // {a.hi16, b.hi16}
}

__device__ __forceinline__ unsigned pkr(float a, float b) {  // relu + pack
  return pk2(fmaxf(a, 0.f), fmaxf(b, 0.f));
}

__device__ __forceinline__ f32x16 zero16() {
  f32x16 z;
#pragma unroll
  for (int i = 0; i < 16; ++i) z[i] = 0.f;
  return z;
}

// B-frag from one c-group's acc (16 floats), parity selects k-step 2c / 2c+1.
__device__ __forceinline__ i32x4 mkfrag(const f32x16& a, int parity) {
  const int b = parity * 8;
  i32x4 v;
  v.x = (int)pkr(a[b + 0], a[b + 1]);
  v.y = (int)pkr(a[b + 2], a[b + 3]);
  v.z = (int)pkr(a[b + 4], a[b + 5]);
  v.w = (int)pkr(a[b + 6], a[b + 7]);
  return v;
}

__device__ __forceinline__ int phi(int k) {  // swap bits 2 and 3
  return (k & ~12) | ((k & 4) << 1) | ((k & 8) >> 1);
}

__global__ __launch_bounds__(256) void prep_kernel(
    const float* __restrict__ W1, const float* __restrict__ b1,
    const float* __restrict__ W2, const float* __restrict__ b2,
    const float* __restrict__ W3, const float* __restrict__ b3,
    unsigned short* __restrict__ blob) {
  int idx = blockIdx.x * 256 + threadIdx.x;
  if (idx >= 3136) return;
  if (idx < 2304) {  // W2 frags: idx = (c*9+s)*64 + lane, k-dim permuted by phi
    int lane = idx & 63;
    int cs = idx >> 6;
    int c = cs / 9, s = cs % 9;
    int h = lane >> 5, f = 32 * c + (lane & 31);
#pragma unroll
    for (int j = 0; j < 8; ++j) {
      int k = 16 * s + 8 * h + j;
      float v = (k < 128) ? W2[phi(k) * 128 + f] : ((k == 128) ? b2[f] : 0.f);
      blob[idx * 8 + j] = f2b(v);
    }
  } else if (idx < 2880) {  // W3 frags (M padded 3->32), k-dim permuted by phi
    int r = idx - 2304;
    int lane = r & 63, s = r >> 6;
    int h = lane >> 5, f = lane & 31;
#pragma unroll
    for (int j = 0; j < 8; ++j) {
      int k = 16 * s + 8 * h + j;
      float v = 0.f;
      if (f < 3) v = (k < 128) ? W3[phi(k) * 3 + f] : ((k == 128) ? b3[f] : 0.f);
      blob[18432 + r * 8 + j] = f2b(v);
    }
  } else {  // W1 frags (K padded 5(+bias)->16), natural
    int r = idx - 2880;
    int lane = r & 63, c = r >> 6;
    int h = lane >> 5, f = 32 * c + (lane & 31);
#pragma unroll
    for (int j = 0; j < 8; ++j) {
      int k = 8 * h + j;
      float v = (k < 5) ? W1[k * 128 + f] : ((k == 5) ? b1[f] : 0.f);
      blob[23040 + r * 8 + j] = f2b(v);
    }
  }
}

// 3 blocks/CU: LDS 50176*3 = 147 KB <= 160 KB; target VGPR <= 170 for
// 3 waves/SIMD (512-reg file / wave-slot). Register-lean schedule: L2 split
// into 4 c-groups, each group's output packed and fed to L3 immediately.
__global__ __launch_bounds__(256, 3) void dyn_kernel(
    const float* __restrict__ S, const float* __restrict__ A,
    const unsigned short* __restrict__ blob, float* __restrict__ out) {
  __shared__ __align__(16) unsigned short lds[25088];
  const int tid = threadIdx.x;
  const int lane = tid & 63;
  const int wv = tid >> 6;
  const int h = lane >> 5;
  const int ln = lane & 31;

  {  // stage whole frag blob (50 KB) into LDS
    const i32x4* src = (const i32x4*)blob;
    i32x4* dst = (i32x4*)lds;
    for (int i = tid; i < 3136; i += 256) dst[i] = src[i];
  }

  const int r0 = blockIdx.x * 256 + wv * 64;  // wave covers rows [r0, r0+64)
  const int row64 = r0 + lane;

  const float sx = S[row64 * 3 + 0], sy = S[row64 * 3 + 1], sz = S[row64 * 3 + 2];
  const float2 a2v = ((const float2*)A)[row64];
  const float ax = a2v.x, ay = a2v.y;

  // ---- reward, fp32, before the barrier (no LDS dependence) ----
  {
    float quad = 30.f * ((sx - ax) * (sx - ax) + (sy - ay) * (sy - ay));
    const float OX[6] = {0.f, 0.f, 0.f, 0.f, 0.f, -0.8f};
    const float OY[6] = {0.f, 0.2f, 0.4f, 0.6f, 0.8f, -0.8f};
    // exp(-d2/(2*VAR)) = exp2(-d2 * C2), C2 = log2(e)/(2*VAR)
    const float C2 = 20.609622817083824f;
    float gs = 0.f;
#pragma unroll
    for (int i = 0; i < 6; ++i) {
      float dx = sx - OX[i], dy = sy - OY[i];
      gs += __builtin_amdgcn_exp2f(-(dx * dx + dy * dy) * C2);
    }
    const float IB = 801.5624162594774f;  // log2(e)/(2*SIG^2)
    float e1 = sx + 1.5f, e2 = sx - 1.5f, e3 = sy - 1.0f, e4 = sy + 1.0f;
    float bnd = __builtin_amdgcn_exp2f(-e1 * e1 * IB) +
                __builtin_amdgcn_exp2f(-e2 * e2 * IB) +
                __builtin_amdgcn_exp2f(-e3 * e3 * IB) +
                __builtin_amdgcn_exp2f(-e4 * e4 * IB);
    out[3 * B_N + row64] = -(quad + 454.72840883398667f * gs + 132.98076013381091f * bnd);
  }

  __syncthreads();

  const i32x4* w2p = (const i32x4*)lds;            // (c*9+s)*64 + lane
  const i32x4* w3p = (const i32x4*)(lds + 18432);  // s*64 + lane
  const i32x4* w1p = (const i32x4*)(lds + 23040);  // c*64 + lane

  // x frags for both 32-sample halves (t=1 data via lane-pair shuffle)
  const float u0 = __shfl_xor(sx, 32, 64), u1 = __shfl_xor(sy, 32, 64);
  const float u2 = __shfl_xor(sz, 32, 64), u3 = __shfl_xor(ax, 32, 64);
  const float u4 = __shfl_xor(ay, 32, 64);

  i32x4 xf[2];
  xf[0].x = h ? 0 : (int)pk2(sx, sy);
  xf[0].y = h ? 0 : (int)pk2(sz, ax);
  xf[0].z = h ? 0 : (int)pk2(ay, 1.0f);
  xf[0].w = 0;
  xf[1].x = h ? 0 : (int)pk2(u0, u1);
  xf[1].y = h ? 0 : (int)pk2(u2, u3);
  xf[1].z = h ? 0 : (int)pk2(u4, 1.0f);
  xf[1].w = 0;

  i32x4 bias_frag;  // B[k=128][*] = 1.0 on h=0 lanes, rest 0
  bias_frag.x = h ? 0 : 0x3F80;
  bias_frag.y = 0; bias_frag.z = 0; bias_frag.w = 0;

  // ---- L1 + pack (per half; one acc1 set live at a time) ----
  i32x4 bf2[2][8];
#pragma unroll
  for (int t = 0; t < 2; ++t) {
    bf16x8 xb = __builtin_bit_cast(bf16x8, xf[t]);
    f32x16 acc1[4];
#pragma unroll
    for (int c = 0; c < 4; ++c)
      acc1[c] = __builtin_amdgcn_mfma_f32_32x32x16_bf16(
          __builtin_bit_cast(bf16x8, w1p[c * 64 + lane]), xb, zero16(), 0, 0, 0);
#pragma unroll
    for (int s = 0; s < 8; ++s) bf2[t][s] = mkfrag(acc1[s >> 1], s & 1);
  }

  // ---- L2 in 4 c-groups, each feeding L3 immediately (caps live regs) ----
  f32x16 acc3[2];
  acc3[0] = zero16();
  acc3[1] = zero16();
#pragma unroll
  for (int g = 0; g < 4; ++g) {
    f32x16 a2g[2];
    a2g[0] = zero16();
    a2g[1] = zero16();
#pragma unroll
    for (int s = 0; s < 9; ++s) {
      bf16x8 aa = __builtin_bit_cast(bf16x8, w2p[(g * 9 + s) * 64 + lane]);
      bf16x8 b0 = __builtin_bit_cast(bf16x8, s < 8 ? bf2[0][s] : bias_frag);
      bf16x8 b1 = __builtin_bit_cast(bf16x8, s < 8 ? bf2[1][s] : bias_frag);
      a2g[0] = __builtin_amdgcn_mfma_f32_32x32x16_bf16(aa, b0, a2g[0], 0, 0, 0);
      a2g[1] = __builtin_amdgcn_mfma_f32_32x32x16_bf16(aa, b1, a2g[1], 0, 0, 0);
    }
#pragma unroll
    for (int p = 0; p < 2; ++p) {
      bf16x8 w3f = __builtin_bit_cast(bf16x8, w3p[(2 * g + p) * 64 + lane]);
#pragma unroll
      for (int t = 0; t < 2; ++t) {
        i32x4 fr = mkfrag(a2g[t], p);
        acc3[t] = __builtin_amdgcn_mfma_f32_32x32x16_bf16(
            w3f, __builtin_bit_cast(bf16x8, fr), acc3[t], 0, 0, 0);
      }
    }
  }
  {  // L3 bias k-step (s=8)
    bf16x8 w3f = __builtin_bit_cast(bf16x8, w3p[8 * 64 + lane]);
    bf16x8 bb = __builtin_bit_cast(bf16x8, bias_frag);
    acc3[0] = __builtin_amdgcn_mfma_f32_32x32x16_bf16(w3f, bb, acc3[0], 0, 0, 0);
    acc3[1] = __builtin_amdgcn_mfma_f32_32x32x16_bf16(w3f, bb, acc3[1], 0, 0, 0);
  }

  // ---- store s_next: C-layout h=0 lanes, regs 0..2 ----
  if (h == 0) {
#pragma unroll
    for (int t = 0; t < 2; ++t) {
      int row = r0 + 32 * t + ln;
      float* p = out + row * 3;
      p[0] = acc3[t][0];
      p[1] = acc3[t][1];
      p[2] = acc3[t][2];
    }
  }
}

extern "C" void kernel_launch(void* const* d_in, const int* in_sizes, int n_in,
                              void* d_out, int out_size, void* d_ws, size_t ws_size,
                              hipStream_t stream) {
  const float* S = (const float*)d_in[0];
  const float* A = (const float*)d_in[1];
  const float* W1 = (const float*)d_in[2];
  const float* b1 = (const float*)d_in[3];
  const float* W2 = (const float*)d_in[4];
  const float* b2 = (const float*)d_in[5];
  const float* W3 = (const float*)d_in[6];
  const float* b3 = (const float*)d_in[7];
  unsigned short* blob = (unsigned short*)d_ws;
  float* out = (float*)d_out;

  prep_kernel<<<dim3(13), dim3(256), 0, stream>>>(W1, b1, W2, b2, W3, b3, blob);
  dyn_kernel<<<dim3(B_N / 256), dim3(256), 0, stream>>>(S, A, blob, out);
}

// Round 6
// 98.290 us; speedup vs baseline: 1.1756x; 1.0485x over previous
//
#include <hip/hip_runtime.h>

#define B_N 524288

typedef __attribute__((ext_vector_type(8))) short bf16x8;
typedef __attribute__((ext_vector_type(16))) float f32x16;
typedef __attribute__((ext_vector_type(4))) int i32x4;

#define GLOBAL_AS __attribute__((address_space(1)))
#define LDS_AS __attribute__((address_space(3)))

// ws blob layout (ushort units):
//   W2 frags: [ ((c*9+s)*64 + lane)*8 + j ]  -> 4*9*64*8 = 18432
//   W3 frags: 18432 + [ (s*64+lane)*8 + j ]  -> 9*64*8   = 4608
//   W1 frags: 23040 + [ (c*64+lane)*8 + j ]  -> 4*64*8   = 2048
// total 25088 ushort = 50176 B
//
// Frag element j on lane: k = 16*s + 8*(lane>>5) + j, f(=m) = 32*c + (lane&31)
// (A-operand k-map verified R2; phi-trick verified R3.)
// phi(k) = k with bits 2<->3 swapped, baked into W2/W3 k-index so the packed
// producer C-layout feeds the next layer's B operand with NO cross-lane ops.

__device__ __forceinline__ unsigned short f2b(float v) {  // RNE, prep only
  unsigned u = __builtin_bit_cast(unsigned, v);
  unsigned r = (u + 0x7FFFu + ((u >> 16) & 1u)) >> 16;
  return (unsigned short)r;
}

// pack 2 floats -> bf16x2 (round-half-up): 2 add + 1 v_perm
__device__ __forceinline__ unsigned pk2(float a, float b) {
  unsigned ua = __builtin_bit_cast(unsigned, a) + 0x8000u;
  unsigned ub = __builtin_bit_cast(unsigned, b) + 0x8000u;
  return __builtin_amdgcn_perm(ub, ua, 0x07060302u);  // {a.hi16, b.hi16}
}

__device__ __forceinline__ unsigned pkr(float a, float b) {  // relu + pack
  return pk2(fmaxf(a, 0.f), fmaxf(b, 0.f));
}

__device__ __forceinline__ f32x16 zero16() {
  f32x16 z;
#pragma unroll
  for (int i = 0; i < 16; ++i) z[i] = 0.f;
  return z;
}

// B-frag from one c-group's acc (16 floats), parity selects k-step 2c / 2c+1.
__device__ __forceinline__ i32x4 mkfrag(const f32x16& a, int parity) {
  const int b = parity * 8;
  i32x4 v;
  v.x = (int)pkr(a[b + 0], a[b + 1]);
  v.y = (int)pkr(a[b + 2], a[b + 3]);
  v.z = (int)pkr(a[b + 4], a[b + 5]);
  v.w = (int)pkr(a[b + 6], a[b + 7]);
  return v;
}

__device__ __forceinline__ int phi(int k) {  // swap bits 2 and 3
  return (k & ~12) | ((k & 4) << 1) | ((k & 8) >> 1);
}

// Element-parallel prep: one thread per blob element (25088). 8x the waves of
// the old chunk-parallel version (52 -> 392), coalesced 2B stores; the
// scattered weight loads ride on L2/L3 with far more memory-level parallelism.
__global__ __launch_bounds__(256) void prep_kernel(
    const float* __restrict__ W1, const float* __restrict__ b1,
    const float* __restrict__ W2, const float* __restrict__ b2,
    const float* __restrict__ W3, const float* __restrict__ b3,
    unsigned short* __restrict__ blob) {
  int idx = blockIdx.x * 256 + threadIdx.x;
  if (idx >= 25088) return;
  int j = idx & 7;
  float v;
  if (idx < 18432) {  // W2: chunk = (c*9+s)*64 + lane, k permuted by phi
    int chunk = idx >> 3;
    int lane = chunk & 63;
    int cs = chunk >> 6;
    int c = cs / 9, s = cs - 9 * c;
    int h = lane >> 5, f = 32 * c + (lane & 31);
    int k = 16 * s + 8 * h + j;
    v = (k < 128) ? W2[phi(k) * 128 + f] : ((k == 128) ? b2[f] : 0.f);
  } else if (idx < 23040) {  // W3 (M padded 3->32), k permuted by phi
    int r = (idx - 18432) >> 3;
    int lane = r & 63, s = r >> 6;
    int h = lane >> 5, f = lane & 31;
    int k = 16 * s + 8 * h + j;
    v = 0.f;
    if (f < 3) v = (k < 128) ? W3[phi(k) * 3 + f] : ((k == 128) ? b3[f] : 0.f);
  } else {  // W1 (K padded 5(+bias)->16), natural
    int r = (idx - 23040) >> 3;
    int lane = r & 63, c = r >> 6;
    int h = lane >> 5, f = 32 * c + (lane & 31);
    int k = 8 * h + j;
    v = (k < 5) ? W1[k * 128 + f] : ((k == 5) ? b1[f] : 0.f);
  }
  blob[idx] = f2b(v);
}

// 3 blocks/CU: LDS 50176*3 = 147 KB <= 160 KB; VGPR target <= 170 for
// 3 waves/SIMD. L2 split into 4 c-groups, each feeding L3 immediately.
// Staging via async global_load_lds (width 16), overlapped with the reward.
__global__ __launch_bounds__(256, 3) void dyn_kernel(
    const float* __restrict__ S, const float* __restrict__ A,
    const unsigned short* __restrict__ blob, float* __restrict__ out) {
  __shared__ __align__(16) unsigned short lds[25088];
  const int tid = threadIdx.x;
  const int lane = tid & 63;
  const int wv = tid >> 6;
  const int h = lane >> 5;
  const int ln = lane & 31;

  {  // async stage whole frag blob (50 KB) into LDS; drained at the barrier.
    const GLOBAL_AS char* g = (const GLOBAL_AS char*)blob;
    LDS_AS char* l = (LDS_AS char*)lds;
#pragma unroll
    for (int i = 0; i < 12; ++i)
      __builtin_amdgcn_global_load_lds(
          (const GLOBAL_AS unsigned*)(g + 16 * (tid + 256 * i)),
          (LDS_AS unsigned*)(l + 16 * (tid + 256 * i)), 16, 0, 0);
    if (tid < 64)  // chunks 3072..3135
      __builtin_amdgcn_global_load_lds(
          (const GLOBAL_AS unsigned*)(g + 16 * (tid + 3072)),
          (LDS_AS unsigned*)(l + 16 * (tid + 3072)), 16, 0, 0);
  }

  const int r0 = blockIdx.x * 256 + wv * 64;  // wave covers rows [r0, r0+64)
  const int row64 = r0 + lane;

  const float sx = S[row64 * 3 + 0], sy = S[row64 * 3 + 1], sz = S[row64 * 3 + 2];
  const float2 a2v = ((const float2*)A)[row64];
  const float ax = a2v.x, ay = a2v.y;

  // ---- reward, fp32, overlapped with the staging DMA ----
  {
    float quad = 30.f * ((sx - ax) * (sx - ax) + (sy - ay) * (sy - ay));
    const float OX[6] = {0.f, 0.f, 0.f, 0.f, 0.f, -0.8f};
    const float OY[6] = {0.f, 0.2f, 0.4f, 0.6f, 0.8f, -0.8f};
    // exp(-d2/(2*VAR)) = exp2(-d2 * C2), C2 = log2(e)/(2*VAR)
    const float C2 = 20.609622817083824f;
    float gs = 0.f;
#pragma unroll
    for (int i = 0; i < 6; ++i) {
      float dx = sx - OX[i], dy = sy - OY[i];
      gs += __builtin_amdgcn_exp2f(-(dx * dx + dy * dy) * C2);
    }
    const float IB = 801.5624162594774f;  // log2(e)/(2*SIG^2)
    float e1 = sx + 1.5f, e2 = sx - 1.5f, e3 = sy - 1.0f, e4 = sy + 1.0f;
    float bnd = __builtin_amdgcn_exp2f(-e1 * e1 * IB) +
                __builtin_amdgcn_exp2f(-e2 * e2 * IB) +
                __builtin_amdgcn_exp2f(-e3 * e3 * IB) +
                __builtin_amdgcn_exp2f(-e4 * e4 * IB);
    out[3 * B_N + row64] = -(quad + 454.72840883398667f * gs + 132.98076013381091f * bnd);
  }

  __syncthreads();

  const i32x4* w2p = (const i32x4*)lds;            // (c*9+s)*64 + lane
  const i32x4* w3p = (const i32x4*)(lds + 18432);  // s*64 + lane
  const i32x4* w1p = (const i32x4*)(lds + 23040);  // c*64 + lane

  // x frags for both 32-sample halves (t=1 data via lane-pair shuffle)
  const float u0 = __shfl_xor(sx, 32, 64), u1 = __shfl_xor(sy, 32, 64);
  const float u2 = __shfl_xor(sz, 32, 64), u3 = __shfl_xor(ax, 32, 64);
  const float u4 = __shfl_xor(ay, 32, 64);

  i32x4 xf[2];
  xf[0].x = h ? 0 : (int)pk2(sx, sy);
  xf[0].y = h ? 0 : (int)pk2(sz, ax);
  xf[0].z = h ? 0 : (int)pk2(ay, 1.0f);
  xf[0].w = 0;
  xf[1].x = h ? 0 : (int)pk2(u0, u1);
  xf[1].y = h ? 0 : (int)pk2(u2, u3);
  xf[1].z = h ? 0 : (int)pk2(u4, 1.0f);
  xf[1].w = 0;

  i32x4 bias_frag;  // B[k=128][*] = 1.0 on h=0 lanes, rest 0
  bias_frag.x = h ? 0 : 0x3F80;
  bias_frag.y = 0; bias_frag.z = 0; bias_frag.w = 0;

  // ---- L1 + pack (per half; one acc1 set live at a time) ----
  i32x4 bf2[2][8];
#pragma unroll
  for (int t = 0; t < 2; ++t) {
    bf16x8 xb = __builtin_bit_cast(bf16x8, xf[t]);
    f32x16 acc1[4];
#pragma unroll
    for (int c = 0; c < 4; ++c)
      acc1[c] = __builtin_amdgcn_mfma_f32_32x32x16_bf16(
          __builtin_bit_cast(bf16x8, w1p[c * 64 + lane]), xb, zero16(), 0, 0, 0);
#pragma unroll
    for (int s = 0; s < 8; ++s) bf2[t][s] = mkfrag(acc1[s >> 1], s & 1);
  }

  // ---- L2 in 4 c-groups, each feeding L3 immediately (caps live regs) ----
  f32x16 acc3[2];
  acc3[0] = zero16();
  acc3[1] = zero16();
#pragma unroll
  for (int g = 0; g < 4; ++g) {
    f32x16 a2g[2];
    a2g[0] = zero16();
    a2g[1] = zero16();
#pragma unroll
    for (int s = 0; s < 9; ++s) {
      bf16x8 aa = __builtin_bit_cast(bf16x8, w2p[(g * 9 + s) * 64 + lane]);
      bf16x8 b0 = __builtin_bit_cast(bf16x8, s < 8 ? bf2[0][s] : bias_frag);
      bf16x8 b1 = __builtin_bit_cast(bf16x8, s < 8 ? bf2[1][s] : bias_frag);
      a2g[0] = __builtin_amdgcn_mfma_f32_32x32x16_bf16(aa, b0, a2g[0], 0, 0, 0);
      a2g[1] = __builtin_amdgcn_mfma_f32_32x32x16_bf16(aa, b1, a2g[1], 0, 0, 0);
    }
#pragma unroll
    for (int p = 0; p < 2; ++p) {
      bf16x8 w3f = __builtin_bit_cast(bf16x8, w3p[(2 * g + p) * 64 + lane]);
#pragma unroll
      for (int t = 0; t < 2; ++t) {
        i32x4 fr = mkfrag(a2g[t], p);
        acc3[t] = __builtin_amdgcn_mfma_f32_32x32x16_bf16(
            w3f, __builtin_bit_cast(bf16x8, fr), acc3[t], 0, 0, 0);
      }
    }
  }
  {  // L3 bias k-step (s=8)
    bf16x8 w3f = __builtin_bit_cast(bf16x8, w3p[8 * 64 + lane]);
    bf16x8 bb = __builtin_bit_cast(bf16x8, bias_frag);
    acc3[0] = __builtin_amdgcn_mfma_f32_32x32x16_bf16(w3f, bb, acc3[0], 0, 0, 0);
    acc3[1] = __builtin_amdgcn_mfma_f32_32x32x16_bf16(w3f, bb, acc3[1], 0, 0, 0);
  }

  // ---- store s_next: C-layout h=0 lanes, regs 0..2 ----
  if (h == 0) {
#pragma unroll
    for (int t = 0; t < 2; ++t) {
      int row = r0 + 32 * t + ln;
      float* p = out + row * 3;
      p[0] = acc3[t][0];
      p[1] = acc3[t][1];
      p[2] = acc3[t][2];
    }
  }
}

extern "C" void kernel_launch(void* const* d_in, const int* in_sizes, int n_in,
                              void* d_out, int out_size, void* d_ws, size_t ws_size,
                              hipStream_t stream) {
  const float* S = (const float*)d_in[0];
  const float* A = (const float*)d_in[1];
  const float* W1 = (const float*)d_in[2];
  const float* b1 = (const float*)d_in[3];
  const float* W2 = (const float*)d_in[4];
  const float* b2 = (const float*)d_in[5];
  const float* W3 = (const float*)d_in[6];
  const float* b3 = (const float*)d_in[7];
  unsigned short* blob = (unsigned short*)d_ws;
  float* out = (float*)d_out;

  prep_kernel<<<dim3(98), dim3(256), 0, stream>>>(W1, b1, W2, b2, W3, b3, blob);
  dyn_kernel<<<dim3(B_N / 256), dim3(256), 0, stream>>>(S, A, blob, out);
}